// Round 1
// baseline (526.009 us; speedup 1.0000x reference)
//
#include <hip/hip_runtime.h>
#include <math.h>

// Problem constants
// x: (B=2, C=32, D=96, H=96, W=96) fp32
// out: (2, 32, 48, 48, 48) fp32
#define HS 0.35355339059327373f   /* 1/(2*sqrt(2)) — 3-stage Haar scale */
#define NSPAT 110592              /* 48^3 */
#define NBN   221184              /* B * 48^3 */

// ---------------------------------------------------------------------------
// K1: per-(b,c) parity sums S[b][c][p][q][r] = sum over x[2i+p][2j+q][2l+r]
// One block per (b,c,d)-plane: 96*96 floats = 2304 float4s, 256 thr * 9.
// ---------------------------------------------------------------------------
__global__ __launch_bounds__(256) void k1_parity(const float* __restrict__ x,
                                                 float* __restrict__ S) {
    int blk = blockIdx.x;            // (b*32+c)*96 + d
    int d   = blk % 96;
    int bc  = blk / 96;
    const float4* x4 = (const float4*)x + (long)blk * 2304;
    int tid = threadIdx.x;
    float aE0 = 0.f, aO0 = 0.f, aE1 = 0.f, aO1 = 0.f;  // [q][r]
#pragma unroll
    for (int i = 0; i < 9; ++i) {
        int f = tid + i * 256;           // < 2304
        float4 v = x4[f];
        int h = f / 24;                  // row within plane
        float e = v.x + v.z, o = v.y + v.w;
        if (h & 1) { aE1 += e; aO1 += o; }
        else       { aE0 += e; aO0 += o; }
    }
#pragma unroll
    for (int m = 32; m; m >>= 1) {
        aE0 += __shfl_xor(aE0, m, 64); aO0 += __shfl_xor(aO0, m, 64);
        aE1 += __shfl_xor(aE1, m, 64); aO1 += __shfl_xor(aO1, m, 64);
    }
    __shared__ float red[4][4];
    int lane = tid & 63, wave = tid >> 6;
    if (lane == 0) { red[wave][0] = aE0; red[wave][1] = aO0;
                     red[wave][2] = aE1; red[wave][3] = aO1; }
    __syncthreads();
    if (tid < 4) {
        float v = red[0][tid] + red[1][tid] + red[2][tid] + red[3][tid];
        int q = tid >> 1, r = tid & 1, p = d & 1;
        atomicAdd(&S[bc * 8 + p * 4 + q * 2 + r], v);
    }
}

// ---------------------------------------------------------------------------
// K2 (tiny): band means -> two attention MLPs -> effective fuse matrix
//   A[b][o][c][pqr] = HS * ( wf[o,c]*ylow[c] +
//                            sum_k sign_k(pqr)*wf[o,32+c*7+k]*yhigh[c*7+k] )
// sign_k flips per detail-dim parity; detail mask for band k is (k+1) in
// pqr-bit order (p=bit2 D, q=bit1 H, r=bit0 W); bands: aad,ada,add,daa,dad,dda,ddd.
// One block per batch b.
// ---------------------------------------------------------------------------
__global__ __launch_bounds__(256) void k2_attn(
        const float* __restrict__ S,
        const float* __restrict__ w1l, const float* __restrict__ w2l,
        const float* __restrict__ w1h, const float* __restrict__ w2h,
        const float* __restrict__ wf, float* __restrict__ A) {
    int b = blockIdx.x, tid = threadIdx.x;
    __shared__ float mlow[32], mhigh[224], h1l[2], h1h[14], ylow[32], yhigh[224];
    const float* Sb = S + b * 256;
    const float MS = HS / (float)NSPAT;   // subband mean scale
    if (tid < 32) {
        float s = 0.f;
        for (int j = 0; j < 8; ++j) s += Sb[tid * 8 + j];
        mlow[tid] = s * MS;
    }
    if (tid < 224) {
        int c = tid / 7, k = tid % 7, dm = k + 1;
        float s = 0.f;
        for (int j = 0; j < 8; ++j) {
            float sg = (__popc(j & dm) & 1) ? -1.f : 1.f;
            s += sg * Sb[c * 8 + j];
        }
        mhigh[tid] = s * MS;
    }
    __syncthreads();
    if (tid < 2) {
        float s = 0.f;
        for (int c = 0; c < 32; ++c) s += w1l[tid * 32 + c] * mlow[c];
        h1l[tid] = fmaxf(s, 0.f);
    } else if (tid < 16) {
        int j = tid - 2;
        float s = 0.f;
        for (int c = 0; c < 224; ++c) s += w1h[j * 224 + c] * mhigh[c];
        h1h[j] = fmaxf(s, 0.f);
    }
    __syncthreads();
    if (tid < 32) {
        float s = w2l[tid * 2] * h1l[0] + w2l[tid * 2 + 1] * h1l[1];
        ylow[tid] = 1.f / (1.f + expf(-s));
    } else if (tid < 256) {
        int i = tid - 32;
        float s = 0.f;
        for (int j = 0; j < 14; ++j) s += w2h[i * 14 + j] * h1h[j];
        yhigh[i] = 1.f / (1.f + expf(-s));
    }
    __syncthreads();
    for (int idx = tid; idx < 8192; idx += 256) {
        int o = idx >> 8, c = (idx >> 3) & 31, pqr = idx & 7;
        float a = wf[o * 256 + c] * ylow[c];
#pragma unroll
        for (int k = 0; k < 7; ++k) {
            float sg = (__popc(pqr & (k + 1)) & 1) ? -1.f : 1.f;
            a += sg * wf[o * 256 + 32 + c * 7 + k] * yhigh[c * 7 + k];
        }
        A[b * 8192 + idx] = a * HS;
    }
}

// ---------------------------------------------------------------------------
// K3 (main): z[b,o,od,oh,ow] = sum_{c,pqr} A[b,o,c,pqr] * x[b,c,2od+p,2oh+q,2ow+r]
// Thread: one (od, oh, ow-pair) for ALL 32 output channels; float4 x loads
// cover 4 input w = 2 output w. Block: 192 thr = 8 oh-rows x 24 ow-pairs.
// A (32KB) staged in LDS; A reads are wave-uniform -> broadcast, conflict-free.
// Also accumulates BN sum/sumsq per output channel (wave butterfly + atomics).
// ---------------------------------------------------------------------------
__global__ __launch_bounds__(192) void k3_main(const float* __restrict__ x,
                                               const float* __restrict__ A,
                                               float* __restrict__ z,
                                               float* __restrict__ bnSum,
                                               float* __restrict__ bnSq) {
    __shared__ float ldsA[8192];
    __shared__ float red[3][64];
    int blk = blockIdx.x;              // 576 = 2 * 48 * 6
    int b   = blk / 288;
    int rem = blk % 288;
    int od  = rem / 6;
    int ohg = rem % 6;
    int tid = threadIdx.x;
    for (int i = tid; i < 8192; i += 192) ldsA[i] = A[b * 8192 + i];
    __syncthreads();

    int row = tid / 24;                // 0..7
    int t   = tid % 24;                // ow-pair: outputs 2t, 2t+1
    int oh  = ohg * 8 + row;

    float acc0[32], acc1[32];
#pragma unroll
    for (int o = 0; o < 32; ++o) { acc0[o] = 0.f; acc1[o] = 0.f; }

    const float4* x4 = (const float4*)x;
    // float4 index for (b, c, 2od+p, 2oh+q, 4t): channel stride 96^3/4 = 221184
    int base = (((b * 32) * 96 + 2 * od) * 96 + 2 * oh) * 24 + t;
    for (int c = 0; c < 32; ++c) {
        int i4 = base + c * 221184;
        float4 v00 = x4[i4];                 // p=0,q=0
        float4 v01 = x4[i4 + 24];            // p=0,q=1 (h+1)
        float4 v10 = x4[i4 + 2304];          // p=1,q=0 (d+1)
        float4 v11 = x4[i4 + 2304 + 24];     // p=1,q=1
        const float* Ac = &ldsA[c * 8];
#pragma unroll
        for (int o = 0; o < 32; ++o) {
            const float4* Ao = (const float4*)(Ac + o * 256);
            float4 a0 = Ao[0];   // pqr = 000,001,010,011
            float4 a1 = Ao[1];   // pqr = 100,101,110,111
            acc0[o] += a0.x * v00.x + a0.y * v00.y + a0.z * v01.x + a0.w * v01.y
                     + a1.x * v10.x + a1.y * v10.y + a1.z * v11.x + a1.w * v11.y;
            acc1[o] += a0.x * v00.z + a0.y * v00.w + a0.z * v01.z + a0.w * v01.w
                     + a1.x * v10.z + a1.y * v10.w + a1.z * v11.z + a1.w * v11.w;
        }
    }

    // write z (staged in d_out), coalesced float2 per o
    float2* z2 = (float2*)z;
#pragma unroll
    for (int o = 0; o < 32; ++o) {
        int zi = (((b * 32 + o) * 48 + od) * 48 + oh) * 24 + t;
        z2[zi] = make_float2(acc0[o], acc1[o]);
    }

    // BN partial sums
    int lane = tid & 63, wave = tid >> 6;
#pragma unroll
    for (int o = 0; o < 32; ++o) {
        float sv = acc0[o] + acc1[o];
        float qv = acc0[o] * acc0[o] + acc1[o] * acc1[o];
#pragma unroll
        for (int m = 32; m; m >>= 1) {
            sv += __shfl_xor(sv, m, 64);
            qv += __shfl_xor(qv, m, 64);
        }
        if (lane == 0) { red[wave][o] = sv; red[wave][32 + o] = qv; }
    }
    __syncthreads();
    if (tid < 64) {
        float v = red[0][tid] + red[1][tid] + red[2][tid];
        if (tid < 32) atomicAdd(&bnSum[tid], v);
        else          atomicAdd(&bnSq[tid - 32], v);
    }
}

// ---------------------------------------------------------------------------
// K4 (tiny): BN scale/shift per output channel. b_fuse cancels under BN.
// ---------------------------------------------------------------------------
__global__ void k4_fin(const float* __restrict__ bnSum, const float* __restrict__ bnSq,
                       const float* __restrict__ gamma, const float* __restrict__ beta,
                       float* __restrict__ scale, float* __restrict__ shift) {
    int o = threadIdx.x;
    if (o < 32) {
        const float invN = 1.f / (float)NBN;
        float mean = bnSum[o] * invN;
        float var  = bnSq[o] * invN - mean * mean;
        float inv  = rsqrtf(var + 1e-5f);
        float sc   = gamma[o] * inv;
        scale[o] = sc;
        shift[o] = beta[o] - mean * sc;
    }
}

// ---------------------------------------------------------------------------
// K5: in-place normalize + ReLU over z (= d_out). 1769472 float4s exactly.
// ---------------------------------------------------------------------------
__global__ __launch_bounds__(256) void k5_norm(float* __restrict__ z,
                                               const float* __restrict__ scale,
                                               const float* __restrict__ shift) {
    int i = blockIdx.x * 256 + threadIdx.x;        // float4 index
    float4* z4 = (float4*)z;
    float4 v = z4[i];
    int o = (i / 27648) & 31;                      // 27648 = 48^3/4
    float sc = scale[o], sh = shift[o];
    v.x = fmaxf(v.x * sc + sh, 0.f);
    v.y = fmaxf(v.y * sc + sh, 0.f);
    v.z = fmaxf(v.z * sc + sh, 0.f);
    v.w = fmaxf(v.w * sc + sh, 0.f);
    z4[i] = v;
}

extern "C" void kernel_launch(void* const* d_in, const int* in_sizes, int n_in,
                              void* d_out, int out_size, void* d_ws, size_t ws_size,
                              hipStream_t stream) {
    const float* x    = (const float*)d_in[0];
    const float* w1l  = (const float*)d_in[1];
    const float* w2l  = (const float*)d_in[2];
    const float* w1h  = (const float*)d_in[3];
    const float* w2h  = (const float*)d_in[4];
    const float* wf   = (const float*)d_in[5];
    // d_in[6] = b_fuse: cancels exactly under training-mode BN (mean subtract)
    const float* gamma = (const float*)d_in[7];
    const float* beta  = (const float*)d_in[8];
    float* out = (float*)d_out;

    float* ws    = (float*)d_ws;
    float* S     = ws;          // 512 floats (zeroed)
    float* bnSum = ws + 512;    // 32 (zeroed)
    float* bnSq  = ws + 544;    // 32 (zeroed)
    float* scale = ws + 576;    // 32
    float* shift = ws + 608;    // 32
    float* A     = ws + 1024;   // 16384 floats

    hipMemsetAsync(d_ws, 0, 640 * sizeof(float), stream);
    k1_parity<<<6144, 256, 0, stream>>>(x, S);
    k2_attn<<<2, 256, 0, stream>>>(S, w1l, w2l, w1h, w2h, wf, A);
    k3_main<<<576, 192, 0, stream>>>(x, A, out, bnSum, bnSq);
    k4_fin<<<1, 64, 0, stream>>>(bnSum, bnSq, gamma, beta, scale, shift);
    k5_norm<<<6912, 256, 0, stream>>>(out, scale, shift);
}

// Round 2
// 468.773 us; speedup vs baseline: 1.1221x; 1.1221x over previous
//
#include <hip/hip_runtime.h>
#include <math.h>

// Problem constants
// x: (B=2, C=32, D=96, H=96, W=96) fp32
// out: (2, 32, 48, 48, 48) fp32
#define HS 0.35355339059327373f   /* 1/(2*sqrt(2)) — 3-stage Haar scale */
#define NSPAT 110592              /* 48^3 */
#define NBN   221184              /* B * 48^3 */

// ---------------------------------------------------------------------------
// K1: per-(b,c) parity sums S[b][c][p][q][r] = sum over x[2i+p][2j+q][2l+r]
// One block per (b,c,d)-plane: 96*96 floats = 2304 float4s, 256 thr * 9.
// ---------------------------------------------------------------------------
__global__ __launch_bounds__(256) void k1_parity(const float* __restrict__ x,
                                                 float* __restrict__ S) {
    int blk = blockIdx.x;            // (b*32+c)*96 + d
    int d   = blk % 96;
    int bc  = blk / 96;
    const float4* x4 = (const float4*)x + (long)blk * 2304;
    int tid = threadIdx.x;
    float aE0 = 0.f, aO0 = 0.f, aE1 = 0.f, aO1 = 0.f;  // [q][r]
#pragma unroll
    for (int i = 0; i < 9; ++i) {
        int f = tid + i * 256;           // < 2304
        float4 v = x4[f];
        int h = f / 24;                  // row within plane (const-div -> magic mul)
        float e = v.x + v.z, o = v.y + v.w;
        if (h & 1) { aE1 += e; aO1 += o; }
        else       { aE0 += e; aO0 += o; }
    }
#pragma unroll
    for (int m = 32; m; m >>= 1) {
        aE0 += __shfl_xor(aE0, m, 64); aO0 += __shfl_xor(aO0, m, 64);
        aE1 += __shfl_xor(aE1, m, 64); aO1 += __shfl_xor(aO1, m, 64);
    }
    __shared__ float red[4][4];
    int lane = tid & 63, wave = tid >> 6;
    if (lane == 0) { red[wave][0] = aE0; red[wave][1] = aO0;
                     red[wave][2] = aE1; red[wave][3] = aO1; }
    __syncthreads();
    if (tid < 4) {
        float v = red[0][tid] + red[1][tid] + red[2][tid] + red[3][tid];
        int q = tid >> 1, r = tid & 1, p = d & 1;
        atomicAdd(&S[bc * 8 + p * 4 + q * 2 + r], v);
    }
}

// ---------------------------------------------------------------------------
// K2 (tiny): band means -> two attention MLPs -> effective fuse matrix
//   A[b][o][c][pqr] = HS * ( wf[o,c]*ylow[c] +
//                            sum_k sign_k(pqr)*wf[o,32+c*7+k]*yhigh[c*7+k] )
// One block per batch b.
// ---------------------------------------------------------------------------
__global__ __launch_bounds__(256) void k2_attn(
        const float* __restrict__ S,
        const float* __restrict__ w1l, const float* __restrict__ w2l,
        const float* __restrict__ w1h, const float* __restrict__ w2h,
        const float* __restrict__ wf, float* __restrict__ A) {
    int b = blockIdx.x, tid = threadIdx.x;
    __shared__ float mlow[32], mhigh[224], h1l[2], h1h[14], ylow[32], yhigh[224];
    const float* Sb = S + b * 256;
    const float MS = HS / (float)NSPAT;   // subband mean scale
    if (tid < 32) {
        float s = 0.f;
        for (int j = 0; j < 8; ++j) s += Sb[tid * 8 + j];
        mlow[tid] = s * MS;
    }
    if (tid < 224) {
        int c = tid / 7, k = tid % 7, dm = k + 1;
        float s = 0.f;
        for (int j = 0; j < 8; ++j) {
            float sg = (__popc(j & dm) & 1) ? -1.f : 1.f;
            s += sg * Sb[c * 8 + j];
        }
        mhigh[tid] = s * MS;
    }
    __syncthreads();
    if (tid < 2) {
        float s = 0.f;
        for (int c = 0; c < 32; ++c) s += w1l[tid * 32 + c] * mlow[c];
        h1l[tid] = fmaxf(s, 0.f);
    } else if (tid < 16) {
        int j = tid - 2;
        float s = 0.f;
        for (int c = 0; c < 224; ++c) s += w1h[j * 224 + c] * mhigh[c];
        h1h[j] = fmaxf(s, 0.f);
    }
    __syncthreads();
    if (tid < 32) {
        float s = w2l[tid * 2] * h1l[0] + w2l[tid * 2 + 1] * h1l[1];
        ylow[tid] = 1.f / (1.f + expf(-s));
    } else if (tid < 256) {
        int i = tid - 32;
        float s = 0.f;
        for (int j = 0; j < 14; ++j) s += w2h[i * 14 + j] * h1h[j];
        yhigh[i] = 1.f / (1.f + expf(-s));
    }
    __syncthreads();
    for (int idx = tid; idx < 8192; idx += 256) {
        int o = idx >> 8, c = (idx >> 3) & 31, pqr = idx & 7;
        float a = wf[o * 256 + c] * ylow[c];
#pragma unroll
        for (int k = 0; k < 7; ++k) {
            float sg = (__popc(pqr & (k + 1)) & 1) ? -1.f : 1.f;
            a += sg * wf[o * 256 + 32 + c * 7 + k] * yhigh[c * 7 + k];
        }
        A[b * 8192 + idx] = a * HS;
    }
}

// ---------------------------------------------------------------------------
// K3 (main): z[b,o,od,oh,ow] = sum_{c,pqr} A[b,o,c,pqr] * x[b,c,2od+p,2oh+q,2ow+r]
// R2: o-split x2 — each block handles 16 output channels (og = blk&1 so the
// two blocks sharing a spatial slab are dispatched adjacently -> L2 sharing).
// Grid 1152 blocks x 192 thr = 13.5 waves/CU (~42% occupancy) vs 6.75 before.
// Per-thread: 32 acc regs (16 o x 2 ow), 32 c-iters x 4 float4 loads x 256 FMA.
// ---------------------------------------------------------------------------
__global__ __launch_bounds__(192) void k3_main(const float* __restrict__ x,
                                               const float* __restrict__ A,
                                               float* __restrict__ z,
                                               float* __restrict__ bnSum,
                                               float* __restrict__ bnSq) {
    __shared__ float ldsA[4096];
    __shared__ float red[3][32];
    int blk = blockIdx.x;              // ((b*48+od)*6+ohg)*2+og : 1152 blocks
    int og  = blk & 1;
    int tmp = blk >> 1;
    int ohg = tmp % 6;
    tmp /= 6;
    int od  = tmp % 48;
    int b   = tmp / 48;
    int tid = threadIdx.x;
    // stage this block's A slice: 16 o x 32 c x 8 pqr = 4096 floats = 16 KB
    const float* Ab = A + b * 8192 + og * 4096;
    for (int i = tid; i < 4096; i += 192) ldsA[i] = Ab[i];
    __syncthreads();

    int row = tid / 24;                // 0..7
    int t   = tid % 24;                // ow-pair: outputs 2t, 2t+1
    int oh  = ohg * 8 + row;

    float acc0[16], acc1[16];
#pragma unroll
    for (int o = 0; o < 16; ++o) { acc0[o] = 0.f; acc1[o] = 0.f; }

    const float4* x4 = (const float4*)x;
    // float4 index for (b, c, 2od+p, 2oh+q, 4t): channel stride 96^3/4 = 221184
    int base = (((b * 32) * 96 + 2 * od) * 96 + 2 * oh) * 24 + t;
    for (int c = 0; c < 32; ++c) {
        int i4 = base + c * 221184;
        float4 v00 = x4[i4];                 // p=0,q=0
        float4 v01 = x4[i4 + 24];            // p=0,q=1 (h+1)
        float4 v10 = x4[i4 + 2304];          // p=1,q=0 (d+1)
        float4 v11 = x4[i4 + 2304 + 24];     // p=1,q=1
        const float* Ac = &ldsA[c * 8];
#pragma unroll
        for (int o = 0; o < 16; ++o) {
            // wave-uniform LDS address -> broadcast, conflict-free
            const float4* Ao = (const float4*)(Ac + o * 256);
            float4 a0 = Ao[0];   // pqr = 000,001,010,011
            float4 a1 = Ao[1];   // pqr = 100,101,110,111
            acc0[o] += a0.x * v00.x + a0.y * v00.y + a0.z * v01.x + a0.w * v01.y
                     + a1.x * v10.x + a1.y * v10.y + a1.z * v11.x + a1.w * v11.y;
            acc1[o] += a0.x * v00.z + a0.y * v00.w + a0.z * v01.z + a0.w * v01.w
                     + a1.x * v10.z + a1.y * v10.w + a1.z * v11.z + a1.w * v11.w;
        }
    }

    // write z (staged in d_out), coalesced float2 per o
    float2* z2 = (float2*)z;
#pragma unroll
    for (int o = 0; o < 16; ++o) {
        int zi = (((b * 32 + og * 16 + o) * 48 + od) * 48 + oh) * 24 + t;
        z2[zi] = make_float2(acc0[o], acc1[o]);
    }

    // BN partial sums for this block's 16 channels
    int lane = tid & 63, wave = tid >> 6;
#pragma unroll
    for (int o = 0; o < 16; ++o) {
        float sv = acc0[o] + acc1[o];
        float qv = acc0[o] * acc0[o] + acc1[o] * acc1[o];
#pragma unroll
        for (int m = 32; m; m >>= 1) {
            sv += __shfl_xor(sv, m, 64);
            qv += __shfl_xor(qv, m, 64);
        }
        if (lane == 0) { red[wave][o] = sv; red[wave][16 + o] = qv; }
    }
    __syncthreads();
    if (tid < 32) {
        float v = red[0][tid] + red[1][tid] + red[2][tid];
        if (tid < 16) atomicAdd(&bnSum[og * 16 + tid], v);
        else          atomicAdd(&bnSq[og * 16 + tid - 16], v);
    }
}

// ---------------------------------------------------------------------------
// K5: BN finalize (per-block recompute, fuses old K4) + normalize + ReLU,
// in place over z (= d_out). 1769472 float4s exactly.
// ---------------------------------------------------------------------------
__global__ __launch_bounds__(256) void k5_norm(float* __restrict__ z,
                                               const float* __restrict__ bnSum,
                                               const float* __restrict__ bnSq,
                                               const float* __restrict__ gamma,
                                               const float* __restrict__ beta) {
    __shared__ float s_sc[32], s_sh[32];
    int tid = threadIdx.x;
    if (tid < 32) {
        const float invN = 1.f / (float)NBN;
        float mean = bnSum[tid] * invN;
        float var  = bnSq[tid] * invN - mean * mean;
        float inv  = rsqrtf(var + 1e-5f);
        float sc   = gamma[tid] * inv;
        s_sc[tid] = sc;
        s_sh[tid] = beta[tid] - mean * sc;
    }
    int i = blockIdx.x * 256 + tid;                // float4 index
    float4* z4 = (float4*)z;
    float4 v = z4[i];                              // load before barrier (indep)
    __syncthreads();
    int o = (i / 27648) & 31;                      // 27648 = 48^3/4
    float sc = s_sc[o], sh = s_sh[o];
    v.x = fmaxf(v.x * sc + sh, 0.f);
    v.y = fmaxf(v.y * sc + sh, 0.f);
    v.z = fmaxf(v.z * sc + sh, 0.f);
    v.w = fmaxf(v.w * sc + sh, 0.f);
    z4[i] = v;
}

extern "C" void kernel_launch(void* const* d_in, const int* in_sizes, int n_in,
                              void* d_out, int out_size, void* d_ws, size_t ws_size,
                              hipStream_t stream) {
    const float* x    = (const float*)d_in[0];
    const float* w1l  = (const float*)d_in[1];
    const float* w2l  = (const float*)d_in[2];
    const float* w1h  = (const float*)d_in[3];
    const float* w2h  = (const float*)d_in[4];
    const float* wf   = (const float*)d_in[5];
    // d_in[6] = b_fuse: cancels exactly under training-mode BN (mean subtract)
    const float* gamma = (const float*)d_in[7];
    const float* beta  = (const float*)d_in[8];
    float* out = (float*)d_out;

    float* ws    = (float*)d_ws;
    float* S     = ws;          // 512 floats (zeroed)
    float* bnSum = ws + 512;    // 32 (zeroed)
    float* bnSq  = ws + 544;    // 32 (zeroed)
    float* A     = ws + 1024;   // 16384 floats

    hipMemsetAsync(d_ws, 0, 576 * sizeof(float), stream);
    k1_parity<<<6144, 256, 0, stream>>>(x, S);
    k2_attn<<<2, 256, 0, stream>>>(S, w1l, w2l, w1h, w2h, wf, A);
    k3_main<<<1152, 192, 0, stream>>>(x, A, out, bnSum, bnSq);
    k5_norm<<<6912, 256, 0, stream>>>(out, bnSum, bnSq, gamma, beta);
}

// Round 3
// 441.355 us; speedup vs baseline: 1.1918x; 1.0621x over previous
//
#include <hip/hip_runtime.h>
#include <math.h>

// Problem constants
// x: (B=2, C=32, D=96, H=96, W=96) fp32
// out: (2, 32, 48, 48, 48) fp32
#define HS 0.35355339059327373f   /* 1/(2*sqrt(2)) — 3-stage Haar scale */
#define NSPAT 110592              /* 48^3 */
#define NBN   221184              /* B * 48^3 */

// ---------------------------------------------------------------------------
// K1: per-(b,c) parity sums S[b][c][p][q][r] = sum over x[2i+p][2j+q][2l+r]
// One block per (b,c,d)-plane: 96*96 floats = 2304 float4s, 256 thr * 9.
// ---------------------------------------------------------------------------
__global__ __launch_bounds__(256) void k1_parity(const float* __restrict__ x,
                                                 float* __restrict__ S) {
    int blk = blockIdx.x;            // (b*32+c)*96 + d
    int d   = blk % 96;
    int bc  = blk / 96;
    const float4* x4 = (const float4*)x + (long)blk * 2304;
    int tid = threadIdx.x;
    float aE0 = 0.f, aO0 = 0.f, aE1 = 0.f, aO1 = 0.f;  // [q][r]
#pragma unroll
    for (int i = 0; i < 9; ++i) {
        int f = tid + i * 256;           // < 2304
        float4 v = x4[f];
        int h = f / 24;                  // row within plane (const-div -> magic mul)
        float e = v.x + v.z, o = v.y + v.w;
        if (h & 1) { aE1 += e; aO1 += o; }
        else       { aE0 += e; aO0 += o; }
    }
#pragma unroll
    for (int m = 32; m; m >>= 1) {
        aE0 += __shfl_xor(aE0, m, 64); aO0 += __shfl_xor(aO0, m, 64);
        aE1 += __shfl_xor(aE1, m, 64); aO1 += __shfl_xor(aO1, m, 64);
    }
    __shared__ float red[4][4];
    int lane = tid & 63, wave = tid >> 6;
    if (lane == 0) { red[wave][0] = aE0; red[wave][1] = aO0;
                     red[wave][2] = aE1; red[wave][3] = aO1; }
    __syncthreads();
    if (tid < 4) {
        float v = red[0][tid] + red[1][tid] + red[2][tid] + red[3][tid];
        int q = tid >> 1, r = tid & 1, p = d & 1;
        atomicAdd(&S[bc * 8 + p * 4 + q * 2 + r], v);
    }
}

// ---------------------------------------------------------------------------
// K2 (tiny): band means -> two attention MLPs -> effective fuse matrix
//   A[b][o][c][pqr] = HS * ( wf[o,c]*ylow[c] +
//                            sum_k sign_k(pqr)*wf[o,32+c*7+k]*yhigh[c*7+k] )
// One block per batch b.
// ---------------------------------------------------------------------------
__global__ __launch_bounds__(256) void k2_attn(
        const float* __restrict__ S,
        const float* __restrict__ w1l, const float* __restrict__ w2l,
        const float* __restrict__ w1h, const float* __restrict__ w2h,
        const float* __restrict__ wf, float* __restrict__ A) {
    int b = blockIdx.x, tid = threadIdx.x;
    __shared__ float mlow[32], mhigh[224], h1l[2], h1h[14], ylow[32], yhigh[224];
    const float* Sb = S + b * 256;
    const float MS = HS / (float)NSPAT;   // subband mean scale
    if (tid < 32) {
        float s = 0.f;
        for (int j = 0; j < 8; ++j) s += Sb[tid * 8 + j];
        mlow[tid] = s * MS;
    }
    if (tid < 224) {
        int c = tid / 7, k = tid % 7, dm = k + 1;
        float s = 0.f;
        for (int j = 0; j < 8; ++j) {
            float sg = (__popc(j & dm) & 1) ? -1.f : 1.f;
            s += sg * Sb[c * 8 + j];
        }
        mhigh[tid] = s * MS;
    }
    __syncthreads();
    if (tid < 2) {
        float s = 0.f;
        for (int c = 0; c < 32; ++c) s += w1l[tid * 32 + c] * mlow[c];
        h1l[tid] = fmaxf(s, 0.f);
    } else if (tid < 16) {
        int j = tid - 2;
        float s = 0.f;
        for (int c = 0; c < 224; ++c) s += w1h[j * 224 + c] * mhigh[c];
        h1h[j] = fmaxf(s, 0.f);
    }
    __syncthreads();
    if (tid < 32) {
        float s = w2l[tid * 2] * h1l[0] + w2l[tid * 2 + 1] * h1l[1];
        ylow[tid] = 1.f / (1.f + expf(-s));
    } else if (tid < 256) {
        int i = tid - 32;
        float s = 0.f;
        for (int j = 0; j < 14; ++j) s += w2h[i * 14 + j] * h1h[j];
        yhigh[i] = 1.f / (1.f + expf(-s));
    }
    __syncthreads();
    for (int idx = tid; idx < 8192; idx += 256) {
        int o = idx >> 8, c = (idx >> 3) & 31, pqr = idx & 7;
        float a = wf[o * 256 + c] * ylow[c];
#pragma unroll
        for (int k = 0; k < 7; ++k) {
            float sg = (__popc(pqr & (k + 1)) & 1) ? -1.f : 1.f;
            a += sg * wf[o * 256 + 32 + c * 7 + k] * yhigh[c * 7 + k];
        }
        A[b * 8192 + idx] = a * HS;
    }
}

// ---------------------------------------------------------------------------
// K3 (main): z[b,o,od,oh,ow] = sum_{c,pqr} A[b,o,c,pqr] * x[b,c,2od+p,2oh+q,2ow+r]
// R3: A read via BLOCK-UNIFORM global loads -> compiler scalarizes to
// s_load into SGPRs (scalar pipe, parallel to VALU; v_fma takes 1 SGPR
// operand free). Removes the 1024 ds_read_b128/thread LDS tax of R2 and the
// 16 KB LDS staging + barrier. c-loop software-pipelined 1 deep so the 4
// global float4 x-loads for c+1 are in flight during c's 256 FMAs.
// Grid 1152 = b(2) x od(48) x ohg(6) x og(2); block 192 = 8 rows x 24 t.
// ---------------------------------------------------------------------------
__global__ __launch_bounds__(192) void k3_main(const float* __restrict__ x,
                                               const float* __restrict__ A,
                                               float* __restrict__ z,
                                               float* __restrict__ bnSum,
                                               float* __restrict__ bnSq) {
    __shared__ float red[3][32];
    int blk = blockIdx.x;              // ((b*48+od)*6+ohg)*2+og
    int og  = blk & 1;
    int tmp = blk >> 1;
    int ohg = tmp % 6;
    tmp /= 6;
    int od  = tmp % 48;
    int b   = tmp / 48;
    int tid = threadIdx.x;
    int row = tid / 24;                // 0..7
    int t   = tid % 24;                // ow-pair: outputs 2t, 2t+1
    int oh  = ohg * 8 + row;

    const float* Ab = A + b * 8192 + og * 4096;  // [o<16][c<32][pqr<8], block-uniform

    float acc0[16], acc1[16];
#pragma unroll
    for (int o = 0; o < 16; ++o) { acc0[o] = 0.f; acc1[o] = 0.f; }

    const float4* x4 = (const float4*)x;
    // float4 index for (b, c, 2od+p, 2oh+q, 4t): channel stride 96^3/4 = 221184
    int base = (((b * 32) * 96 + 2 * od) * 96 + 2 * oh) * 24 + t;

    float4 v00 = x4[base];
    float4 v01 = x4[base + 24];
    float4 v10 = x4[base + 2304];
    float4 v11 = x4[base + 2328];
    for (int c = 0; c < 32; ++c) {
        float4 n00, n01, n10, n11;
        if (c < 31) {
            int i4 = base + (c + 1) * 221184;
            n00 = x4[i4];
            n01 = x4[i4 + 24];
            n10 = x4[i4 + 2304];
            n11 = x4[i4 + 2328];
        }
        const float* Ac = Ab + c * 8;
#pragma unroll
        for (int o = 0; o < 16; ++o) {
            const float* Ao = Ac + o * 256;     // uniform -> SGPRs
            float a0 = Ao[0], a1 = Ao[1], a2 = Ao[2], a3 = Ao[3];
            float a4 = Ao[4], a5 = Ao[5], a6 = Ao[6], a7 = Ao[7];
            acc0[o] += a0 * v00.x + a1 * v00.y + a2 * v01.x + a3 * v01.y
                     + a4 * v10.x + a5 * v10.y + a6 * v11.x + a7 * v11.y;
            acc1[o] += a0 * v00.z + a1 * v00.w + a2 * v01.z + a3 * v01.w
                     + a4 * v10.z + a5 * v10.w + a6 * v11.z + a7 * v11.w;
        }
        v00 = n00; v01 = n01; v10 = n10; v11 = n11;
    }

    // write z (staged in d_out), coalesced float2 per o
    float2* z2 = (float2*)z;
#pragma unroll
    for (int o = 0; o < 16; ++o) {
        int zi = (((b * 32 + og * 16 + o) * 48 + od) * 48 + oh) * 24 + t;
        z2[zi] = make_float2(acc0[o], acc1[o]);
    }

    // BN partial sums for this block's 16 channels
    int lane = tid & 63, wave = tid >> 6;
#pragma unroll
    for (int o = 0; o < 16; ++o) {
        float sv = acc0[o] + acc1[o];
        float qv = acc0[o] * acc0[o] + acc1[o] * acc1[o];
#pragma unroll
        for (int m = 32; m; m >>= 1) {
            sv += __shfl_xor(sv, m, 64);
            qv += __shfl_xor(qv, m, 64);
        }
        if (lane == 0) { red[wave][o] = sv; red[wave][16 + o] = qv; }
    }
    __syncthreads();
    if (tid < 32) {
        float v = red[0][tid] + red[1][tid] + red[2][tid];
        if (tid < 16) atomicAdd(&bnSum[og * 16 + tid], v);
        else          atomicAdd(&bnSq[og * 16 + tid - 16], v);
    }
}

// ---------------------------------------------------------------------------
// K5: BN finalize (per-block recompute) + normalize + ReLU, in place over
// z (= d_out). 1769472 float4s exactly. b_fuse cancels under BN mean-subtract.
// ---------------------------------------------------------------------------
__global__ __launch_bounds__(256) void k5_norm(float* __restrict__ z,
                                               const float* __restrict__ bnSum,
                                               const float* __restrict__ bnSq,
                                               const float* __restrict__ gamma,
                                               const float* __restrict__ beta) {
    __shared__ float s_sc[32], s_sh[32];
    int tid = threadIdx.x;
    if (tid < 32) {
        const float invN = 1.f / (float)NBN;
        float mean = bnSum[tid] * invN;
        float var  = bnSq[tid] * invN - mean * mean;
        float inv  = rsqrtf(var + 1e-5f);
        float sc   = gamma[tid] * inv;
        s_sc[tid] = sc;
        s_sh[tid] = beta[tid] - mean * sc;
    }
    int i = blockIdx.x * 256 + tid;                // float4 index
    float4* z4 = (float4*)z;
    float4 v = z4[i];                              // load before barrier (indep)
    __syncthreads();
    int o = (i / 27648) & 31;                      // 27648 = 48^3/4
    float sc = s_sc[o], sh = s_sh[o];
    v.x = fmaxf(v.x * sc + sh, 0.f);
    v.y = fmaxf(v.y * sc + sh, 0.f);
    v.z = fmaxf(v.z * sc + sh, 0.f);
    v.w = fmaxf(v.w * sc + sh, 0.f);
    z4[i] = v;
}

extern "C" void kernel_launch(void* const* d_in, const int* in_sizes, int n_in,
                              void* d_out, int out_size, void* d_ws, size_t ws_size,
                              hipStream_t stream) {
    const float* x    = (const float*)d_in[0];
    const float* w1l  = (const float*)d_in[1];
    const float* w2l  = (const float*)d_in[2];
    const float* w1h  = (const float*)d_in[3];
    const float* w2h  = (const float*)d_in[4];
    const float* wf   = (const float*)d_in[5];
    // d_in[6] = b_fuse: cancels exactly under training-mode BN (mean subtract)
    const float* gamma = (const float*)d_in[7];
    const float* beta  = (const float*)d_in[8];
    float* out = (float*)d_out;

    float* ws    = (float*)d_ws;
    float* S     = ws;          // 512 floats (zeroed)
    float* bnSum = ws + 512;    // 32 (zeroed)
    float* bnSq  = ws + 544;    // 32 (zeroed)
    float* A     = ws + 1024;   // 16384 floats

    hipMemsetAsync(d_ws, 0, 576 * sizeof(float), stream);
    k1_parity<<<6144, 256, 0, stream>>>(x, S);
    k2_attn<<<2, 256, 0, stream>>>(S, w1l, w2l, w1h, w2h, wf, A);
    k3_main<<<1152, 192, 0, stream>>>(x, A, out, bnSum, bnSq);
    k5_norm<<<6912, 256, 0, stream>>>(out, bnSum, bnSq, gamma, beta);
}